// Round 4
// baseline (285.383 us; speedup 1.0000x reference)
//
#include <hip/hip_runtime.h>
#include <hip/hip_bf16.h>
#include <math.h>
#include <stdio.h>

typedef __hip_bfloat16 bf16;

// ---------------- problem constants ----------------
#define LSEQ 4096
#define DI 128
#define NSTATE 16
#define NK 4
#define NCHUNK 32
#define CLEN 128
#define CHTOT 16384   // 2 scans * 4 k * 128 d * 16 n

// ---------------- fp32 input staging (converted once per call) ----------------
#define IN_X0    0
#define IN_X1    262144
#define IN_IPW0  524288
#define IN_IPW1  540672
#define IN_CW0   557056
#define IN_CB0   558208
#define IN_CW1   558336
#define IN_CB1   559488
#define IN_XPW0  559616
#define IN_DTW0  578048
#define IN_DTW1  580096
#define IN_DTB0  582144
#define IN_DTB1  582656
#define IN_AL0   583168
#define IN_AL1   591360
#define IN_DS0   599552
#define IN_DS1   600064
#define IN_G0    600576
#define IN_B0    600704
#define IN_G1    600832
#define IN_B1    600960
#define IN_WO0   601088
#define IN_WO1   609280
#define END_IN   617472

// ---------------- intermediate buffers ----------------
#define OFF_XC0  END_IN                     // conv in/out branch0, [d][l]
#define OFF_XC1  (OFF_XC0 + DI*LSEQ)
#define OFF_SZ0  (OFF_XC1 + DI*LSEQ)        // silu(z), [l][d]
#define OFF_SZ1  (OFF_SZ0 + LSEQ*DI)
#define OFF_XDBL (OFF_SZ1 + LSEQ*DI)        // [k][36][l]: rows 0-3 dtr, 4-19 B, 20-35 C
#define OFF_CHP  (OFF_XDBL + NK*36*LSEQ)    // [chunk][chain]; after k_comb holds h-init
#define OFF_CHS  (OFF_CHP + NCHUNK*CHTOT)
#define OFF_MG0  (OFF_CHS + NCHUNK*CHTOT)   // merged y, [pixel][d]
#define OFF_MG1  (OFF_MG0 + LSEQ*DI)
#define OFF_FLAG (OFF_MG1 + LSEQ*DI)        // 1.0 if inputs are fp32, 0.0 if bf16
#define WS_FLOATS (OFF_FLAG + 1)            // ~5.4M floats = ~21.6 MB

__device__ __forceinline__ float softplus_f(float x) {
  return x > 20.f ? x : log1pf(__expf(x));
}
__device__ __forceinline__ float silu_f(float x) {
  return x / (1.f + __expf(-x));
}
// scan-position -> pixel index (row-major h*64+w) for direction k
__device__ __forceinline__ int pixmap(int k, int l) {
  if (k == 0) return l;
  if (k == 1) return ((l & 63) << 6) | (l >> 6);
  if (k == 2) return 4095 - l;
  int m = 4095 - l;
  return ((m & 63) << 6) | (m >> 6);
}

// ---------------- K-1: detect input dtype ----------------
// Samples even bf16 indices of in_proj0_w (scale 0.02 => |w| < 0.2 if truly bf16).
// If the buffer is fp32-backed, even bf16 elements are the fp32 words' low
// mantissa halves -> random exponents -> ~50% have |v|>4 or NaN.
__global__ void k_detect(const void* probe, float* __restrict__ ws) {
  int t = threadIdx.x;  // 64 threads
  int idx = 2 * ((t * 127) & 4095);
  float v = __bfloat162float(((const bf16*)probe)[idx]);
  int weird = (!(v == v)) || (fabsf(v) > 4.0f);
  unsigned long long m = __ballot(weird);
  if (t == 0) ws[OFF_FLAG] = (__popcll(m) >= 8) ? 1.f : 0.f;
}

// ---------------- K0a: convert all inputs to fp32 staging ----------------
struct Ptrs { const void* p[23]; };
__constant__ const int g_cnt[23] = {262144, 262144, 16384, 16384, 1152, 128, 1152, 128,
                                    18432, 2048, 2048, 512, 512, 8192, 8192, 512, 512,
                                    128, 128, 128, 128, 8192, 8192};
__constant__ const int g_dst[23] = {IN_X0, IN_X1, IN_IPW0, IN_IPW1, IN_CW0, IN_CB0,
                                    IN_CW1, IN_CB1, IN_XPW0, IN_DTW0, IN_DTW1, IN_DTB0,
                                    IN_DTB1, IN_AL0, IN_AL1, IN_DS0, IN_DS1, IN_G0,
                                    IN_B0, IN_G1, IN_B1, IN_WO0, IN_WO1};
__global__ __launch_bounds__(256) void k_convert(Ptrs pt, float* __restrict__ ws) {
  int f32 = __builtin_amdgcn_readfirstlane((int)ws[OFF_FLAG]);
  int j = blockIdx.y;
  int n = g_cnt[j];
  int gid = blockIdx.x * 256 + threadIdx.x;
  if (gid >= n) return;
  float v;
  if (f32) v = ((const float*)pt.p[j])[gid];
  else v = __bfloat162float(((const bf16*)pt.p[j])[gid]);
  ws[g_dst[j] + gid] = v;
}

// ---------------- K0b: zero the merged accumulators ----------------
__global__ __launch_bounds__(256) void k_zero(float* __restrict__ ws) {
  int gid = blockIdx.x * 256 + threadIdx.x;
  for (int i = gid; i < 2 * LSEQ * DI; i += 512 * 256) ws[OFF_MG0 + i] = 0.f;
}

// ---------------- K1: in_proj (x @ W^T), split xi / silu(z) ----------------
__global__ __launch_bounds__(256) void k_inproj(float* __restrict__ ws) {
  int b = blockIdx.y;
  const float* x = ws + (b ? IN_X1 : IN_X0);
  const float* w = ws + (b ? IN_IPW1 : IN_IPW0);
  float* xi = ws + (b ? OFF_XC1 : OFF_XC0);
  float* sz = ws + (b ? OFF_SZ1 : OFF_SZ0);
  int l0 = blockIdx.x * 16;
  int t = threadIdx.x;
  __shared__ float xs_[16][64];
  for (int i = t; i < 1024; i += 256) xs_[i >> 6][i & 63] = x[l0 * 64 + i];
  __syncthreads();
  int j = t;  // output channel 0..255
  float wr[64];
#pragma unroll
  for (int c = 0; c < 64; c++) wr[c] = w[j * 64 + c];
  float acc[16];
#pragma unroll
  for (int p = 0; p < 16; p++) {
    float a = 0.f;
#pragma unroll
    for (int c = 0; c < 64; c++) a += xs_[p][c] * wr[c];
    acc[p] = a;
  }
  if (j < 128) {
#pragma unroll
    for (int p = 0; p < 16; p++) xi[j * LSEQ + l0 + p] = acc[p];
  } else {
    int d = j - 128;
#pragma unroll
    for (int p = 0; p < 16; p++) sz[(l0 + p) * 128 + d] = silu_f(acc[p]);
  }
}

// ---------------- K2: depthwise 3x3 conv + bias + SiLU (in-place on XC) ----------------
__global__ __launch_bounds__(256) void k_conv(float* __restrict__ ws) {
  int b = blockIdx.y;
  int d = blockIdx.x;
  const float* cw = ws + (b ? IN_CW1 : IN_CW0) + d * 9;
  float bias = (ws + (b ? IN_CB1 : IN_CB0))[d];
  float* xp = ws + (b ? OFF_XC1 : OFF_XC0) + d * LSEQ;
  float wreg[9];
#pragma unroll
  for (int i = 0; i < 9; i++) wreg[i] = cw[i];
  __shared__ float pl[64][64];
  for (int i = threadIdx.x; i < 4096; i += 256) pl[i >> 6][i & 63] = xp[i];
  __syncthreads();
  for (int i = threadIdx.x; i < 4096; i += 256) {
    int h = i >> 6, w = i & 63;
    float a = bias;
#pragma unroll
    for (int kh = 0; kh < 3; kh++) {
      int hh = h + kh - 1;
      if (hh < 0 || hh > 63) continue;
#pragma unroll
      for (int kw = 0; kw < 3; kw++) {
        int ww = w + kw - 1;
        if (ww < 0 || ww > 63) continue;
        a += pl[hh][ww] * wreg[kh * 3 + kw];
      }
    }
    xp[i] = silu_f(a);
  }
}

// ---------------- K3: x_dbl[k,c,l] = sum_d xs0[k,d,l] * W0[k,c,d] ----------------
__global__ __launch_bounds__(256) void k_xdbl(float* __restrict__ ws) {
  int k = blockIdx.y;
  int l0 = blockIdx.x * 64;
  int t = threadIdx.x;
  __shared__ float xt[128][64];
  __shared__ float wl[36][128];
  const float* xc = ws + OFF_XC0;
  const float* xpw = ws + IN_XPW0;
  for (int i = t; i < 128 * 64; i += 256) {
    int d = i >> 6, ll = i & 63;
    xt[d][ll] = xc[d * LSEQ + pixmap(k, l0 + ll)];
  }
  for (int i = t; i < 36 * 128; i += 256) wl[i >> 7][i & 127] = xpw[k * 4608 + i];
  __syncthreads();
  int lane = t & 63;
  int grp = t >> 6;  // 0..3
  float acc[9];
#pragma unroll
  for (int i = 0; i < 9; i++) acc[i] = 0.f;
  for (int d = 0; d < 128; d++) {
    float xv = xt[d][lane];
#pragma unroll
    for (int i = 0; i < 9; i++) acc[i] += xv * wl[grp + i * 4][d];
  }
  float* xd = ws + OFF_XDBL + k * 36 * LSEQ;
#pragma unroll
  for (int i = 0; i < 9; i++) xd[(grp + i * 4) * LSEQ + l0 + lane] = acc[i];
}

// ---------------- K4a: scan pass 1 — per-chunk (P, S); delta recomputed inline ----------------
__global__ __launch_bounds__(256) void k_scan1(float* __restrict__ ws) {
  int s = blockIdx.z;
  int k = blockIdx.y >> 3;
  int dtile = blockIdx.y & 7;
  int c = blockIdx.x;
  int t = threadIdx.x;
  int dl = t >> 4, n = t & 15;       // compute roles
  int rr = dl, lidx = n;             // load roles (same lanes)
  int d = dtile * 16 + dl;
  // cross-wiring: scan of xs0 (s=0) uses dts1/A1; scan of xs1 uses dts0/A0
  const float* xc = ws + (s ? OFF_XC1 : OFF_XC0);
  const float* xd_dt = ws + OFF_XDBL + k * 36 * LSEQ;  // dtr rows 0..3
  const float* Bb = ws + OFF_XDBL + (k * 36 + 4) * LSEQ;
  const float* alog = ws + (s ? IN_AL0 : IN_AL1);
  const float* dtw = ws + (s ? IN_DTW0 : IN_DTW1);
  const float* dtb = ws + (s ? IN_DTB0 : IN_DTB1);
  float A = -__expf(alog[(k * DI + d) * NSTATE + n]);
  float wr0 = dtw[(k * DI + d) * 4 + 0], wr1 = dtw[(k * DI + d) * 4 + 1];
  float wr2 = dtw[(k * DI + d) * 4 + 2], wr3 = dtw[(k * DI + d) * 4 + 3];
  float dbias = dtb[k * DI + d];
  int l0 = c * CLEN;
  float h = 0.f, P = 1.f;
  __shared__ float dls[16][17], uls[16][17], bls[16][17];
  for (int tile = 0; tile < CLEN / 16; tile++) {
    int lg = l0 + tile * 16 + lidx;
    __syncthreads();
    float r0 = xd_dt[lg], r1 = xd_dt[LSEQ + lg], r2 = xd_dt[2 * LSEQ + lg], r3 = xd_dt[3 * LSEQ + lg];
    dls[rr][lidx] = softplus_f(r0 * wr0 + r1 * wr1 + r2 * wr2 + r3 * wr3 + dbias);
    uls[rr][lidx] = xc[d * LSEQ + pixmap(k, lg)];
    bls[rr][lidx] = Bb[rr * LSEQ + lg];
    __syncthreads();
#pragma unroll
    for (int j = 0; j < 16; j++) {
      float de = dls[dl][j];
      float u = uls[dl][j];
      float bv = bls[n][j];
      float da = __expf(de * A);
      h = da * h + de * u * bv;
      P *= da;
    }
  }
  int chain = ((s * 4 + k) * DI + d) * NSTATE + n;
  ws[OFF_CHP + c * CHTOT + chain] = P;
  ws[OFF_CHS + c * CHTOT + chain] = h;
}

// ---------------- K4b: combine chunk summaries; CHP becomes h-init in place ----------------
__global__ __launch_bounds__(256) void k_comb(float* __restrict__ ws) {
  int chain = blockIdx.x * 256 + threadIdx.x;
  float h = 0.f;
  for (int c = 0; c < NCHUNK; c++) {
    float P = ws[OFF_CHP + c * CHTOT + chain];
    float S = ws[OFF_CHS + c * CHTOT + chain];
    ws[OFF_CHP + c * CHTOT + chain] = h;
    h = P * h + S;
  }
}

// ---------------- K4c: scan pass 2 — recompute with init, scatter y+u*D into merged ----------------
__global__ __launch_bounds__(256) void k_scan2(float* __restrict__ ws) {
  int s = blockIdx.z;
  int k = blockIdx.y >> 3;
  int dtile = blockIdx.y & 7;
  int c = blockIdx.x;
  int t = threadIdx.x;
  int dl = t >> 4, n = t & 15;
  int rr = dl, lidx = n;
  int d = dtile * 16 + dl;
  const float* xc = ws + (s ? OFF_XC1 : OFF_XC0);
  const float* xd_dt = ws + OFF_XDBL + k * 36 * LSEQ;
  const float* Bb = ws + OFF_XDBL + (k * 36 + 4) * LSEQ;
  const float* Cb = ws + OFF_XDBL + (k * 36 + 20) * LSEQ;
  const float* alog = ws + (s ? IN_AL0 : IN_AL1);
  const float* dtw = ws + (s ? IN_DTW0 : IN_DTW1);
  const float* dtb = ws + (s ? IN_DTB0 : IN_DTB1);
  const float* Dvec = ws + (s ? IN_DS0 : IN_DS1);
  float* mg = ws + (s ? OFF_MG1 : OFF_MG0);
  float A = -__expf(alog[(k * DI + d) * NSTATE + n]);
  float wr0 = dtw[(k * DI + d) * 4 + 0], wr1 = dtw[(k * DI + d) * 4 + 1];
  float wr2 = dtw[(k * DI + d) * 4 + 2], wr3 = dtw[(k * DI + d) * 4 + 3];
  float dbias = dtb[k * DI + d];
  float Dv = Dvec[k * DI + dtile * 16 + lidx];  // store-role channel = dtile*16 + (t&15)
  int l0 = c * CLEN;
  int chain = ((s * 4 + k) * DI + d) * NSTATE + n;
  float h = ws[OFF_CHP + c * CHTOT + chain];  // h-init from k_comb
  __shared__ float dls[16][17], uls[16][17], bls[16][17], cls[16][17], yt[16][17];
  for (int tile = 0; tile < CLEN / 16; tile++) {
    int lg = l0 + tile * 16 + lidx;
    __syncthreads();
    float r0 = xd_dt[lg], r1 = xd_dt[LSEQ + lg], r2 = xd_dt[2 * LSEQ + lg], r3 = xd_dt[3 * LSEQ + lg];
    dls[rr][lidx] = softplus_f(r0 * wr0 + r1 * wr1 + r2 * wr2 + r3 * wr3 + dbias);
    uls[rr][lidx] = xc[d * LSEQ + pixmap(k, lg)];
    bls[rr][lidx] = Bb[rr * LSEQ + lg];
    cls[rr][lidx] = Cb[rr * LSEQ + lg];
    __syncthreads();
#pragma unroll
    for (int j = 0; j < 16; j++) {
      float de = dls[dl][j];
      float u = uls[dl][j];
      float bv = bls[n][j];
      float da = __expf(de * A);
      h = da * h + de * u * bv;
      float y = h * cls[n][j];
      y += __shfl_xor(y, 1);
      y += __shfl_xor(y, 2);
      y += __shfl_xor(y, 4);
      y += __shfl_xor(y, 8);
      if (n == 0) yt[dl][j] = y;
    }
    __syncthreads();
    {
      int llocal = t >> 4;  // position within tile
      int dloc = t & 15;    // channel within dtile
      int lg2 = l0 + tile * 16 + llocal;
      int pix = pixmap(k, lg2);
      atomicAdd(&mg[pix * DI + dtile * 16 + dloc],
                yt[dloc][llocal] + uls[dloc][llocal] * Dv);
    }
  }
}

// ---------------- K5: LayerNorm + silu(z) gate + out_proj ----------------
__global__ __launch_bounds__(256) void k_post(const float* __restrict__ ws,
                                              void* __restrict__ out) {
  int b = blockIdx.y;
  // Dtype pairing (doc-faithful): fp32 inputs => fp32 output; bf16 inputs => bf16 output.
  int in_f32 = __builtin_amdgcn_readfirstlane((int)ws[OFF_FLAG]);
  const float* mg = ws + (b ? OFF_MG1 : OFF_MG0);
  const float* sz = ws + (b ? OFF_SZ1 : OFF_SZ0);
  const float* g = ws + (b ? IN_G1 : IN_G0);
  const float* be = ws + (b ? IN_B1 : IN_B0);
  const float* wo = ws + (b ? IN_WO1 : IN_WO0);
  int t = threadIdx.x;
  __shared__ float wl[64][129];
  for (int i = t; i < 8192; i += 256) wl[i >> 7][i & 127] = wo[i];
  __shared__ float yl[2][128];
  __shared__ float red[2][2][2];
  int l0 = blockIdx.x * 8;
  for (int pp = 0; pp < 8; pp += 2) {
    int p2 = t >> 7, d = t & 127;
    int l = l0 + pp + p2;
    float v = mg[l * DI + d];
    float s1 = v, s2 = v * v;
#pragma unroll
    for (int m = 1; m < 64; m <<= 1) {
      s1 += __shfl_xor(s1, m);
      s2 += __shfl_xor(s2, m);
    }
    __syncthreads();  // protect red/yl from previous iteration's readers
    if ((t & 63) == 0) {
      red[p2][(t >> 6) & 1][0] = s1;
      red[p2][(t >> 6) & 1][1] = s2;
    }
    __syncthreads();
    float sum = red[p2][0][0] + red[p2][1][0];
    float ssq = red[p2][0][1] + red[p2][1][1];
    float mean = sum * (1.f / 128.f);
    float var = ssq * (1.f / 128.f) - mean * mean;
    float inv = rsqrtf(var + 1e-5f);
    float ya = (v - mean) * inv * g[d] + be[d];
    ya *= sz[l * 128 + d];
    yl[p2][d] = ya;
    __syncthreads();
    if (t < 128) {
      int p2o = t >> 6, m = t & 63;
      int lo = l0 + pp + p2o;
      float a = 0.f;
#pragma unroll 4
      for (int d2 = 0; d2 < 128; d2++) a += yl[p2o][d2] * wl[m][d2];
      int oi = b * (LSEQ * 64) + lo * 64 + m;
      if (in_f32) ((float*)out)[oi] = a;
      else ((bf16*)out)[oi] = __float2bfloat16(a);
    }
  }
}

extern "C" void kernel_launch(void* const* d_in, const int* in_sizes, int n_in,
                              void* d_out, int out_size, void* d_ws, size_t ws_size,
                              hipStream_t stream) {
  float* ws = (float*)d_ws;

  Ptrs pt;
  // map: skip d_in[9] (x_proj_w1, unused per reference quirk)
  const int map[23] = {0, 1, 2, 3, 4, 5, 6, 7, 8, 10, 11, 12, 13, 14, 15, 16, 17,
                       18, 19, 20, 21, 22, 23};
  for (int j = 0; j < 23; j++) pt.p[j] = d_in[map[j]];

  k_detect<<<dim3(1), 64, 0, stream>>>(d_in[2], ws);
  k_convert<<<dim3(1024, 23), 256, 0, stream>>>(pt, ws);
  k_zero<<<dim3(512), 256, 0, stream>>>(ws);
  k_inproj<<<dim3(LSEQ / 16, 2), 256, 0, stream>>>(ws);
  k_conv<<<dim3(DI, 2), 256, 0, stream>>>(ws);
  k_xdbl<<<dim3(LSEQ / 64, NK), 256, 0, stream>>>(ws);
  k_scan1<<<dim3(NCHUNK, 32, 2), 256, 0, stream>>>(ws);
  k_comb<<<dim3(CHTOT / 256), 256, 0, stream>>>(ws);
  k_scan2<<<dim3(NCHUNK, 32, 2), 256, 0, stream>>>(ws);
  k_post<<<dim3(LSEQ / 8, 2), 256, 0, stream>>>(ws, d_out);
}

// Round 5
// 251.761 us; speedup vs baseline: 1.1335x; 1.1335x over previous
//
#include <hip/hip_runtime.h>
#include <hip/hip_bf16.h>
#include <math.h>

typedef __hip_bfloat16 bf16;

// ---------------- problem constants ----------------
#define LSEQ 4096
#define DI 128
#define NSTATE 16
#define NK 4
#define NCHUNK 128
#define CLEN 32
#define CHTOT 16384   // 2 scans * 4 k * 128 d * 16 n

// ---------------- fp32 input staging (converted once per call) ----------------
#define IN_X0    0
#define IN_X1    262144
#define IN_IPW0  524288
#define IN_IPW1  540672
#define IN_CW0   557056
#define IN_CB0   558208
#define IN_CW1   558336
#define IN_CB1   559488
#define IN_XPW0  559616
#define IN_DTW0  578048
#define IN_DTW1  580096
#define IN_DTB0  582144
#define IN_DTB1  582656
#define IN_AL0   583168
#define IN_AL1   591360
#define IN_DS0   599552
#define IN_DS1   600064
#define IN_G0    600576
#define IN_B0    600704
#define IN_G1    600832
#define IN_B1    600960
#define IN_WO0   601088
#define IN_WO1   609280
#define END_IN   617472

// ---------------- intermediate buffers ----------------
#define OFF_XC0  END_IN                     // conv out branch0, [d][l] (row-major pixels)
#define OFF_XC1  (OFF_XC0 + DI*LSEQ)
#define OFF_XT0  (OFF_XC1 + DI*LSEQ)        // transposed plane, [d][w*64+h]
#define OFF_XT1  (OFF_XT0 + DI*LSEQ)
#define OFF_SZ0  (OFF_XT1 + DI*LSEQ)        // silu(z), [l][d]
#define OFF_SZ1  (OFF_SZ0 + LSEQ*DI)
#define OFF_XDBL (OFF_SZ1 + LSEQ*DI)        // [k][36][l]: rows 0-3 dtr, 4-19 B, 20-35 C
#define OFF_CHP  (OFF_XDBL + NK*36*LSEQ)    // [chunk][chain]; after k_comb holds h-init
#define OFF_CHS  (OFF_CHP + NCHUNK*CHTOT)
#define OFF_MG0  (OFF_CHS + NCHUNK*CHTOT)   // merged y, [pixel][d]
#define OFF_MG1  (OFF_MG0 + LSEQ*DI)
#define OFF_FLAG (OFF_MG1 + LSEQ*DI)        // 1.0 if inputs are fp32, 0.0 if bf16
#define WS_FLOATS (OFF_FLAG + 1)

__device__ __forceinline__ float softplus_f(float x) {
  return x > 20.f ? x : log1pf(__expf(x));
}
__device__ __forceinline__ float silu_f(float x) {
  return x / (1.f + __expf(-x));
}
// scan-position -> pixel index (row-major h*64+w) for direction k
__device__ __forceinline__ int pixmap(int k, int l) {
  if (k == 0) return l;
  if (k == 1) return ((l & 63) << 6) | (l >> 6);
  if (k == 2) return 4095 - l;
  int m = 4095 - l;
  return ((m & 63) << 6) | (m >> 6);
}

// ---------------- K-1: detect input dtype ----------------
__global__ void k_detect(const void* probe, float* __restrict__ ws) {
  int t = threadIdx.x;  // 64 threads
  int idx = 2 * ((t * 127) & 4095);
  float v = __bfloat162float(((const bf16*)probe)[idx]);
  int weird = (!(v == v)) || (fabsf(v) > 4.0f);
  unsigned long long m = __ballot(weird);
  if (t == 0) ws[OFF_FLAG] = (__popcll(m) >= 8) ? 1.f : 0.f;
}

// ---------------- K0a: convert all inputs to fp32 staging ----------------
struct Ptrs { const void* p[23]; };
__constant__ const int g_cnt[23] = {262144, 262144, 16384, 16384, 1152, 128, 1152, 128,
                                    18432, 2048, 2048, 512, 512, 8192, 8192, 512, 512,
                                    128, 128, 128, 128, 8192, 8192};
__constant__ const int g_dst[23] = {IN_X0, IN_X1, IN_IPW0, IN_IPW1, IN_CW0, IN_CB0,
                                    IN_CW1, IN_CB1, IN_XPW0, IN_DTW0, IN_DTW1, IN_DTB0,
                                    IN_DTB1, IN_AL0, IN_AL1, IN_DS0, IN_DS1, IN_G0,
                                    IN_B0, IN_G1, IN_B1, IN_WO0, IN_WO1};
__global__ __launch_bounds__(256) void k_convert(Ptrs pt, float* __restrict__ ws) {
  int f32 = __builtin_amdgcn_readfirstlane((int)ws[OFF_FLAG]);
  int j = blockIdx.y;
  int n = g_cnt[j];
  int gid = blockIdx.x * 256 + threadIdx.x;
  if (gid >= n) return;
  float v;
  if (f32) v = ((const float*)pt.p[j])[gid];
  else v = __bfloat162float(((const bf16*)pt.p[j])[gid]);
  ws[g_dst[j] + gid] = v;
}

// ---------------- K0b: zero the merged accumulators ----------------
__global__ __launch_bounds__(256) void k_zero(float* __restrict__ ws) {
  int gid = blockIdx.x * 256 + threadIdx.x;
  for (int i = gid; i < 2 * LSEQ * DI; i += 512 * 256) ws[OFF_MG0 + i] = 0.f;
}

// ---------------- K1: in_proj (x @ W^T), split xi / silu(z) ----------------
__global__ __launch_bounds__(256) void k_inproj(float* __restrict__ ws) {
  int b = blockIdx.y;
  const float* x = ws + (b ? IN_X1 : IN_X0);
  const float* w = ws + (b ? IN_IPW1 : IN_IPW0);
  float* xi = ws + (b ? OFF_XC1 : OFF_XC0);
  float* sz = ws + (b ? OFF_SZ1 : OFF_SZ0);
  int l0 = blockIdx.x * 16;
  int t = threadIdx.x;
  __shared__ float xs_[16][64];
  for (int i = t; i < 1024; i += 256) xs_[i >> 6][i & 63] = x[l0 * 64 + i];
  __syncthreads();
  int j = t;  // output channel 0..255
  float wr[64];
#pragma unroll
  for (int c = 0; c < 64; c++) wr[c] = w[j * 64 + c];
  float acc[16];
#pragma unroll
  for (int p = 0; p < 16; p++) {
    float a = 0.f;
#pragma unroll
    for (int c = 0; c < 64; c++) a += xs_[p][c] * wr[c];
    acc[p] = a;
  }
  if (j < 128) {
#pragma unroll
    for (int p = 0; p < 16; p++) xi[j * LSEQ + l0 + p] = acc[p];
  } else {
    int d = j - 128;
#pragma unroll
    for (int p = 0; p < 16; p++) sz[(l0 + p) * 128 + d] = silu_f(acc[p]);
  }
}

// ---------------- K2: depthwise 3x3 conv + bias + SiLU; emit xc and transposed xcT ----------------
__global__ __launch_bounds__(256) void k_conv(float* __restrict__ ws) {
  int b = blockIdx.y;
  int d = blockIdx.x;
  const float* cw = ws + (b ? IN_CW1 : IN_CW0) + d * 9;
  float bias = (ws + (b ? IN_CB1 : IN_CB0))[d];
  float* xp = ws + (b ? OFF_XC1 : OFF_XC0) + d * LSEQ;
  float* xt = ws + (b ? OFF_XT1 : OFF_XT0) + d * LSEQ;
  float wreg[9];
#pragma unroll
  for (int i = 0; i < 9; i++) wreg[i] = cw[i];
  __shared__ float pl[64][64];
  __shared__ float po[64][65];
  for (int i = threadIdx.x; i < 4096; i += 256) pl[i >> 6][i & 63] = xp[i];
  __syncthreads();
  for (int i = threadIdx.x; i < 4096; i += 256) {
    int h = i >> 6, w = i & 63;
    float a = bias;
#pragma unroll
    for (int kh = 0; kh < 3; kh++) {
      int hh = h + kh - 1;
      if (hh < 0 || hh > 63) continue;
#pragma unroll
      for (int kw = 0; kw < 3; kw++) {
        int ww = w + kw - 1;
        if (ww < 0 || ww > 63) continue;
        a += pl[hh][ww] * wreg[kh * 3 + kw];
      }
    }
    float r = silu_f(a);
    xp[i] = r;
    po[w][h] = r;  // transposed stash
  }
  __syncthreads();
  for (int i = threadIdx.x; i < 4096; i += 256) xt[i] = po[i >> 6][i & 63];
}

// ---------------- K3: x_dbl[k,c,l] = sum_d xs0[k,d,l] * W0[k,c,d] ----------------
__global__ __launch_bounds__(256) void k_xdbl(float* __restrict__ ws) {
  int k = blockIdx.y;
  int l0 = blockIdx.x * 64;
  int t = threadIdx.x;
  __shared__ float xtile[128][64];
  __shared__ float wl[36][128];
  const float* pk = ws + ((k & 1) ? OFF_XT0 : OFF_XC0);  // branch0 planes
  int rev = (k >= 2);
  const float* xpw = ws + IN_XPW0;
  for (int i = t; i < 128 * 64; i += 256) {
    int d = i >> 6, ll = i & 63;
    int idx = rev ? (4095 - (l0 + ll)) : (l0 + ll);
    xtile[d][ll] = pk[d * LSEQ + idx];
  }
  for (int i = t; i < 36 * 128; i += 256) wl[i >> 7][i & 127] = xpw[k * 4608 + i];
  __syncthreads();
  int lane = t & 63;
  int grp = t >> 6;  // 0..3
  float acc[9];
#pragma unroll
  for (int i = 0; i < 9; i++) acc[i] = 0.f;
  for (int d = 0; d < 128; d++) {
    float xv = xtile[d][lane];
#pragma unroll
    for (int i = 0; i < 9; i++) acc[i] += xv * wl[grp + i * 4][d];
  }
  float* xd = ws + OFF_XDBL + k * 36 * LSEQ;
#pragma unroll
  for (int i = 0; i < 9; i++) xd[(grp + i * 4) * LSEQ + l0 + lane] = acc[i];
}

// ---------------- scan helpers ----------------
// thread owns (s,k,d) chain, 16 n-states in registers.
// cross-wiring: s=0 scans xs0 with dt1/A1/D1 params; s=1 scans xs1 with dt0/A0/D0.

// ---------------- K4a: scan pass 1 — per-chunk (P, S) ----------------
__global__ __launch_bounds__(128) void k_scanA(float* __restrict__ ws) {
  int s = blockIdx.z, k = blockIdx.y, c = blockIdx.x;
  int d = threadIdx.x;  // 0..127
  const float* xd_dt = ws + OFF_XDBL + k * 36 * LSEQ;
  const float* Bb = ws + OFF_XDBL + (k * 36 + 4) * LSEQ;
  const float* alog = ws + (s ? IN_AL0 : IN_AL1);
  const float* dtw = ws + (s ? IN_DTW0 : IN_DTW1);
  const float* dtb = ws + (s ? IN_DTB0 : IN_DTB1);
  const float* uplane = ws + ((s ? OFF_XC1 : OFF_XC0) + ((k & 1) ? 2 * DI * LSEQ : 0)) + d * LSEQ;
  int rev = (k >= 2);
  float A[NSTATE];
#pragma unroll
  for (int n = 0; n < NSTATE; n++) A[n] = -__expf(alog[(k * DI + d) * NSTATE + n]);
  float4 wrv = *(const float4*)&dtw[(k * DI + d) * 4];
  float dbias = dtb[k * DI + d];
  float h[NSTATE];
#pragma unroll
  for (int n = 0; n < NSTATE; n++) h[n] = 0.f;
  float sde = 0.f;
  __shared__ float dtr_s[4][16];
  __shared__ __align__(16) float Bt[16][16];
  int l0 = c * CLEN;
  for (int tile = 0; tile < CLEN / 16; tile++) {
    int l0t = l0 + tile * 16;
    __syncthreads();
    if (d < 64) dtr_s[d >> 4][d & 15] = xd_dt[(d >> 4) * LSEQ + l0t + (d & 15)];
#pragma unroll
    for (int q = 0; q < 2; q++) {
      int i = d + q * 128;
      int n = i >> 4, j = i & 15;
      Bt[j][n] = Bb[n * LSEQ + l0t + j];
    }
    __syncthreads();
    float de[16];
#pragma unroll
    for (int j = 0; j < 16; j++) {
      de[j] = softplus_f(dtr_s[0][j] * wrv.x + dtr_s[1][j] * wrv.y +
                         dtr_s[2][j] * wrv.z + dtr_s[3][j] * wrv.w + dbias);
      sde += de[j];
    }
    int boff = rev ? (4080 - l0t) : l0t;
    float4 q0 = *(const float4*)&uplane[boff];
    float4 q1 = *(const float4*)&uplane[boff + 4];
    float4 q2 = *(const float4*)&uplane[boff + 8];
    float4 q3 = *(const float4*)&uplane[boff + 12];
    float uu[16] = {q0.x, q0.y, q0.z, q0.w, q1.x, q1.y, q1.z, q1.w,
                    q2.x, q2.y, q2.z, q2.w, q3.x, q3.y, q3.z, q3.w};
#pragma unroll
    for (int j = 0; j < 16; j++) {
      float u = rev ? uu[15 - j] : uu[j];
      float duj = de[j] * u;
      float4 b0 = *(const float4*)&Bt[j][0];
      float4 b1 = *(const float4*)&Bt[j][4];
      float4 b2 = *(const float4*)&Bt[j][8];
      float4 b3 = *(const float4*)&Bt[j][12];
      float bv[16] = {b0.x, b0.y, b0.z, b0.w, b1.x, b1.y, b1.z, b1.w,
                      b2.x, b2.y, b2.z, b2.w, b3.x, b3.y, b3.z, b3.w};
#pragma unroll
      for (int n = 0; n < NSTATE; n++) {
        float da = __expf(de[j] * A[n]);
        h[n] = da * h[n] + duj * bv[n];
      }
    }
  }
  int chainb = ((s * 4 + k) * DI + d) * NSTATE;
  float* Pp = ws + OFF_CHP + c * CHTOT + chainb;
  float* Sp = ws + OFF_CHS + c * CHTOT + chainb;
#pragma unroll
  for (int n = 0; n < NSTATE; n++) {
    Pp[n] = __expf(A[n] * sde);
    Sp[n] = h[n];
  }
}

// ---------------- K4b: combine chunk summaries; CHP becomes h-init in place ----------------
__global__ __launch_bounds__(256) void k_comb(float* __restrict__ ws) {
  int chain = blockIdx.x * 256 + threadIdx.x;
  float* P = ws + OFF_CHP + chain;
  float* S = ws + OFF_CHS + chain;
  float h = 0.f;
  float p = P[0], sv = S[0];
  for (int c = 0; c < NCHUNK; c++) {
    float pn = 0.f, sn = 0.f;
    if (c + 1 < NCHUNK) {
      pn = P[(c + 1) * CHTOT];
      sn = S[(c + 1) * CHTOT];
    }
    P[c * CHTOT] = h;
    h = p * h + sv;
    p = pn;
    sv = sn;
  }
}

// ---------------- K4c: scan pass 2 — recompute with init, scatter y+u*D into merged ----------------
__global__ __launch_bounds__(128) void k_scanB(float* __restrict__ ws) {
  int s = blockIdx.z, k = blockIdx.y, c = blockIdx.x;
  int d = threadIdx.x;
  const float* xd_dt = ws + OFF_XDBL + k * 36 * LSEQ;
  const float* Bb = ws + OFF_XDBL + (k * 36 + 4) * LSEQ;
  const float* Cb = ws + OFF_XDBL + (k * 36 + 20) * LSEQ;
  const float* alog = ws + (s ? IN_AL0 : IN_AL1);
  const float* dtw = ws + (s ? IN_DTW0 : IN_DTW1);
  const float* dtb = ws + (s ? IN_DTB0 : IN_DTB1);
  const float* Dvec = ws + (s ? IN_DS0 : IN_DS1);
  const float* uplane = ws + ((s ? OFF_XC1 : OFF_XC0) + ((k & 1) ? 2 * DI * LSEQ : 0)) + d * LSEQ;
  float* mg = ws + (s ? OFF_MG1 : OFF_MG0);
  int rev = (k >= 2);
  float A[NSTATE];
#pragma unroll
  for (int n = 0; n < NSTATE; n++) A[n] = -__expf(alog[(k * DI + d) * NSTATE + n]);
  float4 wrv = *(const float4*)&dtw[(k * DI + d) * 4];
  float dbias = dtb[k * DI + d];
  float Dv = Dvec[k * DI + d];
  int chainb = ((s * 4 + k) * DI + d) * NSTATE;
  const float* Hp = ws + OFF_CHP + c * CHTOT + chainb;
  float h[NSTATE];
#pragma unroll
  for (int n = 0; n < NSTATE; n++) h[n] = Hp[n];
  __shared__ float dtr_s[4][16];
  __shared__ __align__(16) float Bt[16][16];
  __shared__ __align__(16) float Ct[16][16];
  int l0 = c * CLEN;
  for (int tile = 0; tile < CLEN / 16; tile++) {
    int l0t = l0 + tile * 16;
    __syncthreads();
    if (d < 64) dtr_s[d >> 4][d & 15] = xd_dt[(d >> 4) * LSEQ + l0t + (d & 15)];
#pragma unroll
    for (int q = 0; q < 2; q++) {
      int i = d + q * 128;
      int n = i >> 4, j = i & 15;
      Bt[j][n] = Bb[n * LSEQ + l0t + j];
      Ct[j][n] = Cb[n * LSEQ + l0t + j];
    }
    __syncthreads();
    float de[16];
#pragma unroll
    for (int j = 0; j < 16; j++) {
      de[j] = softplus_f(dtr_s[0][j] * wrv.x + dtr_s[1][j] * wrv.y +
                         dtr_s[2][j] * wrv.z + dtr_s[3][j] * wrv.w + dbias);
    }
    int boff = rev ? (4080 - l0t) : l0t;
    float4 q0 = *(const float4*)&uplane[boff];
    float4 q1 = *(const float4*)&uplane[boff + 4];
    float4 q2 = *(const float4*)&uplane[boff + 8];
    float4 q3 = *(const float4*)&uplane[boff + 12];
    float uu[16] = {q0.x, q0.y, q0.z, q0.w, q1.x, q1.y, q1.z, q1.w,
                    q2.x, q2.y, q2.z, q2.w, q3.x, q3.y, q3.z, q3.w};
#pragma unroll
    for (int j = 0; j < 16; j++) {
      float u = rev ? uu[15 - j] : uu[j];
      float duj = de[j] * u;
      float4 b0 = *(const float4*)&Bt[j][0];
      float4 b1 = *(const float4*)&Bt[j][4];
      float4 b2 = *(const float4*)&Bt[j][8];
      float4 b3 = *(const float4*)&Bt[j][12];
      float bv[16] = {b0.x, b0.y, b0.z, b0.w, b1.x, b1.y, b1.z, b1.w,
                      b2.x, b2.y, b2.z, b2.w, b3.x, b3.y, b3.z, b3.w};
      float4 c0 = *(const float4*)&Ct[j][0];
      float4 c1 = *(const float4*)&Ct[j][4];
      float4 c2 = *(const float4*)&Ct[j][8];
      float4 c3 = *(const float4*)&Ct[j][12];
      float cv[16] = {c0.x, c0.y, c0.z, c0.w, c1.x, c1.y, c1.z, c1.w,
                      c2.x, c2.y, c2.z, c2.w, c3.x, c3.y, c3.z, c3.w};
      float y = 0.f;
#pragma unroll
      for (int n = 0; n < NSTATE; n++) {
        float da = __expf(de[j] * A[n]);
        h[n] = da * h[n] + duj * bv[n];
        y += h[n] * cv[n];
      }
      y += u * Dv;
      int pix = pixmap(k, l0t + j);
      atomicAdd(&mg[pix * DI + d], y);
    }
  }
}

// ---------------- K5: LayerNorm + silu(z) gate + out_proj ----------------
__global__ __launch_bounds__(256) void k_post(const float* __restrict__ ws,
                                              void* __restrict__ out) {
  int b = blockIdx.y;
  int in_f32 = __builtin_amdgcn_readfirstlane((int)ws[OFF_FLAG]);
  const float* mg = ws + (b ? OFF_MG1 : OFF_MG0);
  const float* sz = ws + (b ? OFF_SZ1 : OFF_SZ0);
  const float* g = ws + (b ? IN_G1 : IN_G0);
  const float* be = ws + (b ? IN_B1 : IN_B0);
  const float* wo = ws + (b ? IN_WO1 : IN_WO0);
  int t = threadIdx.x;
  __shared__ float wl[64][129];
  for (int i = t; i < 8192; i += 256) wl[i >> 7][i & 127] = wo[i];
  __shared__ float yl[2][128];
  __shared__ float red[2][2][2];
  int l0 = blockIdx.x * 8;
  for (int pp = 0; pp < 8; pp += 2) {
    int p2 = t >> 7, d = t & 127;
    int l = l0 + pp + p2;
    float v = mg[l * DI + d];
    float s1 = v, s2 = v * v;
#pragma unroll
    for (int m = 1; m < 64; m <<= 1) {
      s1 += __shfl_xor(s1, m);
      s2 += __shfl_xor(s2, m);
    }
    __syncthreads();
    if ((t & 63) == 0) {
      red[p2][(t >> 6) & 1][0] = s1;
      red[p2][(t >> 6) & 1][1] = s2;
    }
    __syncthreads();
    float sum = red[p2][0][0] + red[p2][1][0];
    float ssq = red[p2][0][1] + red[p2][1][1];
    float mean = sum * (1.f / 128.f);
    float var = ssq * (1.f / 128.f) - mean * mean;
    float inv = rsqrtf(var + 1e-5f);
    float ya = (v - mean) * inv * g[d] + be[d];
    ya *= sz[l * 128 + d];
    yl[p2][d] = ya;
    __syncthreads();
    if (t < 128) {
      int p2o = t >> 6, m = t & 63;
      int lo = l0 + pp + p2o;
      float a = 0.f;
#pragma unroll 4
      for (int d2 = 0; d2 < 128; d2++) a += yl[p2o][d2] * wl[m][d2];
      int oi = b * (LSEQ * 64) + lo * 64 + m;
      if (in_f32) ((float*)out)[oi] = a;
      else ((bf16*)out)[oi] = __float2bfloat16(a);
    }
  }
}

extern "C" void kernel_launch(void* const* d_in, const int* in_sizes, int n_in,
                              void* d_out, int out_size, void* d_ws, size_t ws_size,
                              hipStream_t stream) {
  float* ws = (float*)d_ws;

  Ptrs pt;
  const int map[23] = {0, 1, 2, 3, 4, 5, 6, 7, 8, 10, 11, 12, 13, 14, 15, 16, 17,
                       18, 19, 20, 21, 22, 23};
  for (int j = 0; j < 23; j++) pt.p[j] = d_in[map[j]];

  k_detect<<<dim3(1), 64, 0, stream>>>(d_in[2], ws);
  k_convert<<<dim3(1024, 23), 256, 0, stream>>>(pt, ws);
  k_zero<<<dim3(512), 256, 0, stream>>>(ws);
  k_inproj<<<dim3(LSEQ / 16, 2), 256, 0, stream>>>(ws);
  k_conv<<<dim3(DI, 2), 256, 0, stream>>>(ws);
  k_xdbl<<<dim3(LSEQ / 64, NK), 256, 0, stream>>>(ws);
  k_scanA<<<dim3(NCHUNK, NK, 2), 128, 0, stream>>>(ws);
  k_comb<<<dim3(CHTOT / 256), 256, 0, stream>>>(ws);
  k_scanB<<<dim3(NCHUNK, NK, 2), 128, 0, stream>>>(ws);
  k_post<<<dim3(LSEQ / 8, 2), 256, 0, stream>>>(ws, d_out);
}

// Round 6
// 236.835 us; speedup vs baseline: 1.2050x; 1.0630x over previous
//
#include <hip/hip_runtime.h>
#include <hip/hip_bf16.h>
#include <math.h>

typedef __hip_bfloat16 bf16;

// ---------------- problem constants ----------------
#define LSEQ 4096
#define DI 128
#define NSTATE 16
#define NK 4
#define NCHUNK 128
#define CLEN 32
#define CHTOT 16384   // 2 scans * 4 k * 128 d * 16 n

// ---------------- fp32 input staging (packed, converted once per call) ----------------
#define IN_X0    0
#define IN_X1    262144
#define IN_IPW0  524288
#define IN_IPW1  540672
#define IN_CW0   557056
#define IN_CB0   558208
#define IN_CW1   558336
#define IN_CB1   559488
#define IN_XPW0  559616
#define IN_DTW0  578048
#define IN_DTW1  580096
#define IN_DTB0  582144
#define IN_DTB1  582656
#define IN_AL0   583168
#define IN_AL1   591360
#define IN_DS0   599552
#define IN_DS1   600064
#define IN_G0    600576
#define IN_B0    600704
#define IN_G1    600832
#define IN_B1    600960
#define IN_WO0   601088
#define IN_WO1   609280
#define END_IN   617472

// ---------------- intermediate buffers ----------------
#define OFF_XC0  END_IN                     // conv out branch0, [d][l] (row-major pixels)
#define OFF_XC1  (OFF_XC0 + DI*LSEQ)
#define OFF_XT0  (OFF_XC1 + DI*LSEQ)        // transposed plane, [d][w*64+h]
#define OFF_XT1  (OFF_XT0 + DI*LSEQ)
#define OFF_SZ0  (OFF_XT1 + DI*LSEQ)        // silu(z), [l][d]
#define OFF_SZ1  (OFF_SZ0 + LSEQ*DI)
#define OFF_XDBL (OFF_SZ1 + LSEQ*DI)        // [k][36][l]: rows 0-3 dtr, 4-19 B, 20-35 C
#define OFF_CHP  (OFF_XDBL + NK*36*LSEQ)    // [chunk][chain]; after k_comb holds h-init
#define OFF_CHS  (OFF_CHP + NCHUNK*CHTOT)
#define OFF_MG0  (OFF_CHS + NCHUNK*CHTOT)   // merged y, [pixel][d]
#define OFF_MG1  (OFF_MG0 + LSEQ*DI)
#define WS_FLOATS (OFF_MG1 + LSEQ*DI)

#define NZERO (2*LSEQ*DI)

__device__ __forceinline__ float softplus_f(float x) {
  return x > 20.f ? x : __logf(1.f + __expf(x));
}
__device__ __forceinline__ float silu_f(float x) {
  return x / (1.f + __expf(-x));
}
// scan-position -> pixel index (row-major h*64+w) for direction k
__device__ __forceinline__ int pixmap(int k, int l) {
  if (k == 0) return l;
  if (k == 1) return ((l & 63) << 6) | (l >> 6);
  if (k == 2) return 4095 - l;
  int m = 4095 - l;
  return ((m & 63) << 6) | (m >> 6);
}
// inline dtype probe: wave 0 samples even bf16 indices of in_proj0_w.
// fp32-backed buffer -> even bf16 halves have random exponents -> many |v|>4/NaN.
__device__ __forceinline__ int probe_f32(const void* probe, int t, int* sh) {
  if (t < 64) {
    int idx = 2 * ((t * 127) & 4095);
    float v = __bfloat162float(((const bf16*)probe)[idx]);
    int weird = (!(v == v)) || (fabsf(v) > 4.0f);
    unsigned long long m = __ballot(weird);
    if (t == 0) *sh = (__popcll(m) >= 8) ? 1 : 0;
  }
  __syncthreads();
  return *sh;
}

// ---------------- K0: convert inputs to fp32 staging + zero merged accum ----------------
struct Ptrs { const void* p[23]; };
__constant__ const int g_cnt[23] = {262144, 262144, 16384, 16384, 1152, 128, 1152, 128,
                                    18432, 2048, 2048, 512, 512, 8192, 8192, 512, 512,
                                    128, 128, 128, 128, 8192, 8192};
__constant__ const int g_dst[23] = {IN_X0, IN_X1, IN_IPW0, IN_IPW1, IN_CW0, IN_CB0,
                                    IN_CW1, IN_CB1, IN_XPW0, IN_DTW0, IN_DTW1, IN_DTB0,
                                    IN_DTB1, IN_AL0, IN_AL1, IN_DS0, IN_DS1, IN_G0,
                                    IN_B0, IN_G1, IN_B1, IN_WO0, IN_WO1};
__global__ __launch_bounds__(256) void k_convert(Ptrs pt, const void* probe,
                                                 float* __restrict__ ws) {
  __shared__ int sf32;
  int t = threadIdx.x;
  int f32 = probe_f32(probe, t, &sf32);
  int gid = blockIdx.x * 256 + t;
  if (gid < END_IN) {
    int j = 0;
#pragma unroll
    for (int q = 0; q < 22; q++)
      if (gid >= g_dst[q] + g_cnt[q]) j = q + 1;
    int off = gid - g_dst[j];
    float v;
    if (f32) v = ((const float*)pt.p[j])[off];
    else v = __bfloat162float(((const bf16*)pt.p[j])[off]);
    ws[gid] = v;
  } else {
    int z = gid - END_IN;
    if (z < NZERO) ws[OFF_MG0 + z] = 0.f;
  }
}

// ---------------- K1: in_proj (x @ W^T), split xi / silu(z) ----------------
__global__ __launch_bounds__(256) void k_inproj(float* __restrict__ ws) {
  int b = blockIdx.y;
  const float* x = ws + (b ? IN_X1 : IN_X0);
  const float* w = ws + (b ? IN_IPW1 : IN_IPW0);
  float* xi = ws + (b ? OFF_XC1 : OFF_XC0);
  float* sz = ws + (b ? OFF_SZ1 : OFF_SZ0);
  int l0 = blockIdx.x * 16;
  int t = threadIdx.x;
  __shared__ float xs_[16][64];
  for (int i = t; i < 1024; i += 256) xs_[i >> 6][i & 63] = x[l0 * 64 + i];
  __syncthreads();
  int j = t;  // output channel 0..255
  float wr[64];
#pragma unroll
  for (int c = 0; c < 64; c++) wr[c] = w[j * 64 + c];
  float acc[16];
#pragma unroll
  for (int p = 0; p < 16; p++) {
    float a = 0.f;
#pragma unroll
    for (int c = 0; c < 64; c++) a += xs_[p][c] * wr[c];
    acc[p] = a;
  }
  if (j < 128) {
#pragma unroll
    for (int p = 0; p < 16; p++) xi[j * LSEQ + l0 + p] = acc[p];
  } else {
    int d = j - 128;
#pragma unroll
    for (int p = 0; p < 16; p++) sz[(l0 + p) * 128 + d] = silu_f(acc[p]);
  }
}

// ---------------- K2: depthwise 3x3 conv + bias + SiLU; emit xc and transposed xcT ----------------
__global__ __launch_bounds__(256) void k_conv(float* __restrict__ ws) {
  int b = blockIdx.y;
  int d = blockIdx.x;
  const float* cw = ws + (b ? IN_CW1 : IN_CW0) + d * 9;
  float bias = (ws + (b ? IN_CB1 : IN_CB0))[d];
  float* xp = ws + (b ? OFF_XC1 : OFF_XC0) + d * LSEQ;
  float* xt = ws + (b ? OFF_XT1 : OFF_XT0) + d * LSEQ;
  float wreg[9];
#pragma unroll
  for (int i = 0; i < 9; i++) wreg[i] = cw[i];
  __shared__ float pl[64][64];
  __shared__ float po[64][65];
  for (int i = threadIdx.x; i < 4096; i += 256) pl[i >> 6][i & 63] = xp[i];
  __syncthreads();
  for (int i = threadIdx.x; i < 4096; i += 256) {
    int h = i >> 6, w = i & 63;
    float a = bias;
#pragma unroll
    for (int kh = 0; kh < 3; kh++) {
      int hh = h + kh - 1;
      if (hh < 0 || hh > 63) continue;
#pragma unroll
      for (int kw = 0; kw < 3; kw++) {
        int ww = w + kw - 1;
        if (ww < 0 || ww > 63) continue;
        a += pl[hh][ww] * wreg[kh * 3 + kw];
      }
    }
    float r = silu_f(a);
    xp[i] = r;
    po[w][h] = r;  // transposed stash
  }
  __syncthreads();
  for (int i = threadIdx.x; i < 4096; i += 256) xt[i] = po[i >> 6][i & 63];
}

// ---------------- K3: x_dbl[k,c,l] = sum_d xs0[k,d,l] * W0[k,c,d] ----------------
__global__ __launch_bounds__(256) void k_xdbl(float* __restrict__ ws) {
  int k = blockIdx.y;
  int l0 = blockIdx.x * 64;
  int t = threadIdx.x;
  __shared__ float xtile[128][64];
  __shared__ float wl[36][128];
  const float* pk = ws + ((k & 1) ? OFF_XT0 : OFF_XC0);  // branch0 planes
  int rev = (k >= 2);
  const float* xpw = ws + IN_XPW0;
  for (int i = t; i < 128 * 64; i += 256) {
    int d = i >> 6, ll = i & 63;
    int idx = rev ? (4095 - (l0 + ll)) : (l0 + ll);
    xtile[d][ll] = pk[d * LSEQ + idx];
  }
  for (int i = t; i < 36 * 128; i += 256) wl[i >> 7][i & 127] = xpw[k * 4608 + i];
  __syncthreads();
  int lane = t & 63;
  int grp = t >> 6;  // 0..3
  float acc[9];
#pragma unroll
  for (int i = 0; i < 9; i++) acc[i] = 0.f;
  for (int d = 0; d < 128; d++) {
    float xv = xtile[d][lane];
#pragma unroll
    for (int i = 0; i < 9; i++) acc[i] += xv * wl[grp + i * 4][d];
  }
  float* xd = ws + OFF_XDBL + k * 36 * LSEQ;
#pragma unroll
  for (int i = 0; i < 9; i++) xd[(grp + i * 4) * LSEQ + l0 + lane] = acc[i];
}

// ---------------- scan kernels ----------------
// thread owns a (s,k,d) chain with 16 n-states in registers.
// cross-wiring: s=0 scans xs0 with dt1/A1/D1 params; s=1 scans xs1 with dt0/A0/D0.
// Fast path: A_logs = log(1..16) => A[n] = (n+1)*A[0]  =>  exp(de*A[n]) = e1^(n+1).
// Detected per-thread against the actual data; falls back to 16 exps if violated.

// ---------------- K4a: scan pass 1 — per-chunk (P, S) ----------------
__global__ __launch_bounds__(128, 2) void k_scanA(float* __restrict__ ws) {
  int s = blockIdx.z, k = blockIdx.y, c = blockIdx.x;
  int d = threadIdx.x;  // 0..127
  const float* xd_dt = ws + OFF_XDBL + k * 36 * LSEQ;
  const float* Bb = ws + OFF_XDBL + (k * 36 + 4) * LSEQ;
  const float* alog = ws + (s ? IN_AL0 : IN_AL1);
  const float* dtw = ws + (s ? IN_DTW0 : IN_DTW1);
  const float* dtb = ws + (s ? IN_DTB0 : IN_DTB1);
  const float* uplane = ws + ((s ? OFF_XC1 : OFF_XC0) + ((k & 1) ? 2 * DI * LSEQ : 0)) + d * LSEQ;
  int rev = (k >= 2);
  float A[NSTATE];
#pragma unroll
  for (int n = 0; n < NSTATE; n++) A[n] = -__expf(alog[(k * DI + d) * NSTATE + n]);
  bool fast = true;
#pragma unroll
  for (int n = 1; n < NSTATE; n++)
    fast = fast && (fabsf(A[n] - (float)(n + 1) * A[0]) <= 1e-3f * fabsf(A[n]));
  float4 wrv = *(const float4*)&dtw[(k * DI + d) * 4];
  float dbias = dtb[k * DI + d];
  float h[NSTATE];
#pragma unroll
  for (int n = 0; n < NSTATE; n++) h[n] = 0.f;
  float sde = 0.f;
  __shared__ float dtr_s[4][16];
  __shared__ __align__(16) float Bt[16 * 20];  // row stride 20: write-conflict-free, 16B-aligned
  int l0 = c * CLEN;
  for (int tile = 0; tile < CLEN / 16; tile++) {
    int l0t = l0 + tile * 16;
    __syncthreads();
    if (d < 64) dtr_s[d >> 4][d & 15] = xd_dt[(d >> 4) * LSEQ + l0t + (d & 15)];
#pragma unroll
    for (int q = 0; q < 2; q++) {
      int i = d + q * 128;
      int n = i >> 4, j = i & 15;
      Bt[j * 20 + n] = Bb[n * LSEQ + l0t + j];
    }
    __syncthreads();
    float de[16];
#pragma unroll
    for (int j = 0; j < 16; j++) {
      de[j] = softplus_f(dtr_s[0][j] * wrv.x + dtr_s[1][j] * wrv.y +
                         dtr_s[2][j] * wrv.z + dtr_s[3][j] * wrv.w + dbias);
      sde += de[j];
    }
    int boff = rev ? (4080 - l0t) : l0t;
    float4 q0 = *(const float4*)&uplane[boff];
    float4 q1 = *(const float4*)&uplane[boff + 4];
    float4 q2 = *(const float4*)&uplane[boff + 8];
    float4 q3 = *(const float4*)&uplane[boff + 12];
    float uu[16] = {q0.x, q0.y, q0.z, q0.w, q1.x, q1.y, q1.z, q1.w,
                    q2.x, q2.y, q2.z, q2.w, q3.x, q3.y, q3.z, q3.w};
#pragma unroll
    for (int j = 0; j < 16; j++) {
      float u = rev ? uu[15 - j] : uu[j];
      float duj = de[j] * u;
      float4 b0 = *(const float4*)&Bt[j * 20 + 0];
      float4 b1 = *(const float4*)&Bt[j * 20 + 4];
      float4 b2 = *(const float4*)&Bt[j * 20 + 8];
      float4 b3 = *(const float4*)&Bt[j * 20 + 12];
      float bv[16] = {b0.x, b0.y, b0.z, b0.w, b1.x, b1.y, b1.z, b1.w,
                      b2.x, b2.y, b2.z, b2.w, b3.x, b3.y, b3.z, b3.w};
      if (fast) {
        float e1 = __expf(de[j] * A[0]);
        float p = e1;
#pragma unroll
        for (int n = 0; n < NSTATE; n++) {
          h[n] = p * h[n] + duj * bv[n];
          p *= e1;
        }
      } else {
#pragma unroll
        for (int n = 0; n < NSTATE; n++) {
          float da = __expf(de[j] * A[n]);
          h[n] = da * h[n] + duj * bv[n];
        }
      }
    }
  }
  int chainb = ((s * 4 + k) * DI + d) * NSTATE;
  float* Pp = ws + OFF_CHP + c * CHTOT + chainb;
  float* Sp = ws + OFF_CHS + c * CHTOT + chainb;
#pragma unroll
  for (int n = 0; n < NSTATE; n++) {
    Pp[n] = __expf(A[n] * sde);
    Sp[n] = h[n];
  }
}

// ---------------- K4b: combine chunk summaries; CHP becomes h-init in place ----------------
__global__ __launch_bounds__(256) void k_comb(float* __restrict__ ws) {
  int chain = blockIdx.x * 256 + threadIdx.x;
  float* P = ws + OFF_CHP + chain;
  float* S = ws + OFF_CHS + chain;
  float h = 0.f;
  for (int g = 0; g < NCHUNK; g += 8) {
    float p[8], sv[8];
#pragma unroll
    for (int i = 0; i < 8; i++) {
      p[i] = P[(g + i) * CHTOT];
      sv[i] = S[(g + i) * CHTOT];
    }
#pragma unroll
    for (int i = 0; i < 8; i++) {
      P[(g + i) * CHTOT] = h;
      h = p[i] * h + sv[i];
    }
  }
}

// ---------------- K4c: scan pass 2 — recompute with init, scatter y+u*D into merged ----------------
__global__ __launch_bounds__(128, 2) void k_scanB(float* __restrict__ ws) {
  int s = blockIdx.z, k = blockIdx.y, c = blockIdx.x;
  int d = threadIdx.x;
  const float* xd_dt = ws + OFF_XDBL + k * 36 * LSEQ;
  const float* Bb = ws + OFF_XDBL + (k * 36 + 4) * LSEQ;
  const float* Cb = ws + OFF_XDBL + (k * 36 + 20) * LSEQ;
  const float* alog = ws + (s ? IN_AL0 : IN_AL1);
  const float* dtw = ws + (s ? IN_DTW0 : IN_DTW1);
  const float* dtb = ws + (s ? IN_DTB0 : IN_DTB1);
  const float* Dvec = ws + (s ? IN_DS0 : IN_DS1);
  const float* uplane = ws + ((s ? OFF_XC1 : OFF_XC0) + ((k & 1) ? 2 * DI * LSEQ : 0)) + d * LSEQ;
  float* mg = ws + (s ? OFF_MG1 : OFF_MG0);
  int rev = (k >= 2);
  float A[NSTATE];
#pragma unroll
  for (int n = 0; n < NSTATE; n++) A[n] = -__expf(alog[(k * DI + d) * NSTATE + n]);
  bool fast = true;
#pragma unroll
  for (int n = 1; n < NSTATE; n++)
    fast = fast && (fabsf(A[n] - (float)(n + 1) * A[0]) <= 1e-3f * fabsf(A[n]));
  float4 wrv = *(const float4*)&dtw[(k * DI + d) * 4];
  float dbias = dtb[k * DI + d];
  float Dv = Dvec[k * DI + d];
  int chainb = ((s * 4 + k) * DI + d) * NSTATE;
  const float* Hp = ws + OFF_CHP + c * CHTOT + chainb;
  float h[NSTATE];
#pragma unroll
  for (int n = 0; n < NSTATE; n++) h[n] = Hp[n];
  __shared__ float dtr_s[4][16];
  __shared__ __align__(16) float Bt[16 * 20];
  __shared__ __align__(16) float Ct[16 * 20];
  int l0 = c * CLEN;
  for (int tile = 0; tile < CLEN / 16; tile++) {
    int l0t = l0 + tile * 16;
    __syncthreads();
    if (d < 64) dtr_s[d >> 4][d & 15] = xd_dt[(d >> 4) * LSEQ + l0t + (d & 15)];
#pragma unroll
    for (int q = 0; q < 2; q++) {
      int i = d + q * 128;
      int n = i >> 4, j = i & 15;
      Bt[j * 20 + n] = Bb[n * LSEQ + l0t + j];
      Ct[j * 20 + n] = Cb[n * LSEQ + l0t + j];
    }
    __syncthreads();
    float de[16];
#pragma unroll
    for (int j = 0; j < 16; j++) {
      de[j] = softplus_f(dtr_s[0][j] * wrv.x + dtr_s[1][j] * wrv.y +
                         dtr_s[2][j] * wrv.z + dtr_s[3][j] * wrv.w + dbias);
    }
    int boff = rev ? (4080 - l0t) : l0t;
    float4 q0 = *(const float4*)&uplane[boff];
    float4 q1 = *(const float4*)&uplane[boff + 4];
    float4 q2 = *(const float4*)&uplane[boff + 8];
    float4 q3 = *(const float4*)&uplane[boff + 12];
    float uu[16] = {q0.x, q0.y, q0.z, q0.w, q1.x, q1.y, q1.z, q1.w,
                    q2.x, q2.y, q2.z, q2.w, q3.x, q3.y, q3.z, q3.w};
#pragma unroll
    for (int j = 0; j < 16; j++) {
      float u = rev ? uu[15 - j] : uu[j];
      float duj = de[j] * u;
      float4 b0 = *(const float4*)&Bt[j * 20 + 0];
      float4 b1 = *(const float4*)&Bt[j * 20 + 4];
      float4 b2 = *(const float4*)&Bt[j * 20 + 8];
      float4 b3 = *(const float4*)&Bt[j * 20 + 12];
      float bv[16] = {b0.x, b0.y, b0.z, b0.w, b1.x, b1.y, b1.z, b1.w,
                      b2.x, b2.y, b2.z, b2.w, b3.x, b3.y, b3.z, b3.w};
      float4 c0 = *(const float4*)&Ct[j * 20 + 0];
      float4 c1 = *(const float4*)&Ct[j * 20 + 4];
      float4 c2 = *(const float4*)&Ct[j * 20 + 8];
      float4 c3 = *(const float4*)&Ct[j * 20 + 12];
      float cv[16] = {c0.x, c0.y, c0.z, c0.w, c1.x, c1.y, c1.z, c1.w,
                      c2.x, c2.y, c2.z, c2.w, c3.x, c3.y, c3.z, c3.w};
      float y = 0.f;
      if (fast) {
        float e1 = __expf(de[j] * A[0]);
        float p = e1;
#pragma unroll
        for (int n = 0; n < NSTATE; n++) {
          h[n] = p * h[n] + duj * bv[n];
          y += h[n] * cv[n];
          p *= e1;
        }
      } else {
#pragma unroll
        for (int n = 0; n < NSTATE; n++) {
          float da = __expf(de[j] * A[n]);
          h[n] = da * h[n] + duj * bv[n];
          y += h[n] * cv[n];
        }
      }
      y += u * Dv;
      int pix = pixmap(k, l0t + j);
      atomicAdd(&mg[pix * DI + d], y);
    }
  }
}

// ---------------- K5: LayerNorm + silu(z) gate + out_proj ----------------
__global__ __launch_bounds__(256) void k_post(const float* __restrict__ ws,
                                              const void* probe,
                                              void* __restrict__ out) {
  int b = blockIdx.y;
  __shared__ int sf32;
  int t = threadIdx.x;
  int in_f32 = probe_f32(probe, t, &sf32);
  const float* mg = ws + (b ? OFF_MG1 : OFF_MG0);
  const float* sz = ws + (b ? OFF_SZ1 : OFF_SZ0);
  const float* g = ws + (b ? IN_G1 : IN_G0);
  const float* be = ws + (b ? IN_B1 : IN_B0);
  const float* wo = ws + (b ? IN_WO1 : IN_WO0);
  __shared__ float wl[64][129];
  for (int i = t; i < 8192; i += 256) wl[i >> 7][i & 127] = wo[i];
  __shared__ float yl[2][128];
  __shared__ float red[2][2][2];
  int l0 = blockIdx.x * 32;
  for (int pp = 0; pp < 32; pp += 2) {
    int p2 = t >> 7, d = t & 127;
    int l = l0 + pp + p2;
    float v = mg[l * DI + d];
    float s1 = v, s2 = v * v;
#pragma unroll
    for (int m = 1; m < 64; m <<= 1) {
      s1 += __shfl_xor(s1, m);
      s2 += __shfl_xor(s2, m);
    }
    __syncthreads();
    if ((t & 63) == 0) {
      red[p2][(t >> 6) & 1][0] = s1;
      red[p2][(t >> 6) & 1][1] = s2;
    }
    __syncthreads();
    float sum = red[p2][0][0] + red[p2][1][0];
    float ssq = red[p2][0][1] + red[p2][1][1];
    float mean = sum * (1.f / 128.f);
    float var = ssq * (1.f / 128.f) - mean * mean;
    float inv = rsqrtf(var + 1e-5f);
    float ya = (v - mean) * inv * g[d] + be[d];
    ya *= sz[l * 128 + d];
    yl[p2][d] = ya;
    __syncthreads();
    if (t < 128) {
      int p2o = t >> 6, m = t & 63;
      int lo = l0 + pp + p2o;
      float a = 0.f;
#pragma unroll 4
      for (int d2 = 0; d2 < 128; d2++) a += yl[p2o][d2] * wl[m][d2];
      int oi = b * (LSEQ * 64) + lo * 64 + m;
      if (in_f32) ((float*)out)[oi] = a;
      else ((bf16*)out)[oi] = __float2bfloat16(a);
    }
  }
}

extern "C" void kernel_launch(void* const* d_in, const int* in_sizes, int n_in,
                              void* d_out, int out_size, void* d_ws, size_t ws_size,
                              hipStream_t stream) {
  float* ws = (float*)d_ws;

  Ptrs pt;
  const int map[23] = {0, 1, 2, 3, 4, 5, 6, 7, 8, 10, 11, 12, 13, 14, 15, 16, 17,
                       18, 19, 20, 21, 22, 23};
  for (int j = 0; j < 23; j++) pt.p[j] = d_in[map[j]];

  int conv_blocks = (END_IN + NZERO + 255) / 256;
  k_convert<<<dim3(conv_blocks), 256, 0, stream>>>(pt, d_in[2], ws);
  k_inproj<<<dim3(LSEQ / 16, 2), 256, 0, stream>>>(ws);
  k_conv<<<dim3(DI, 2), 256, 0, stream>>>(ws);
  k_xdbl<<<dim3(LSEQ / 64, NK), 256, 0, stream>>>(ws);
  k_scanA<<<dim3(NCHUNK, NK, 2), 128, 0, stream>>>(ws);
  k_comb<<<dim3(CHTOT / 256), 256, 0, stream>>>(ws);
  k_scanB<<<dim3(NCHUNK, NK, 2), 128, 0, stream>>>(ws);
  k_post<<<dim3(LSEQ / 32, 2), 256, 0, stream>>>(ws, d_in[2], d_out);
}